// Round 1
// baseline (754.557 us; speedup 1.0000x reference)
//
#include <hip/hip_runtime.h>
#include <hip/hip_bf16.h>

#define S_LEN 2048
#define HID 4096
#define NH 32
#define NKV 8
#define HD 128

typedef __attribute__((ext_vector_type(4))) float f32x4;
typedef __attribute__((ext_vector_type(8))) __bf16 bf16x8;
typedef __attribute__((ext_vector_type(8))) unsigned short u16x8;
typedef __attribute__((ext_vector_type(4))) unsigned short u16x4;

static __device__ __forceinline__ unsigned short f2bf(float x) {
  return __builtin_bit_cast(unsigned short, __float2bfloat16(x));
}
static __device__ __forceinline__ float bf2f(unsigned short u) {
  return __builtin_bit_cast(float, (unsigned int)u << 16);
}

// ---------------- RoPE table ----------------
__global__ void rope_table(float* cs) {
  int idx = blockIdx.x * blockDim.x + threadIdx.x;
  if (idx >= S_LEN * 64) return;
  int d = idx & 63;
  int p = idx >> 6;
  // inv_freq = theta^(-d/64), theta = 1e6 ; log2(1e6) = 19.9315685693...
  float invf = exp2f(-(float)d * (19.9315685693241741f / 64.0f));
  float ang = (float)p * invf;
  cs[idx] = cosf(ang);
  cs[S_LEN * 64 + idx] = sinf(ang);
}

// ---------------- RoPE apply (in-place, bf16 buffers) ----------------
__global__ void rope_apply(unsigned short* __restrict__ buf, const float* __restrict__ cs, int total) {
  int idx = blockIdx.x * blockDim.x + threadIdx.x;
  if (idx >= total) return;            // total = nheads * S * 64
  int d = idx & 63;
  int hp = idx >> 6;                   // head*S + pos
  int pos = hp & (S_LEN - 1);
  size_t base = (size_t)hp * HD;
  float c = cs[pos * 64 + d];
  float s = cs[S_LEN * 64 + pos * 64 + d];
  float x1 = bf2f(buf[base + d]);
  float x2 = bf2f(buf[base + 64 + d]);
  buf[base + d] = f2bf(x1 * c - x2 * s);
  buf[base + 64 + d] = f2bf(x2 * c + x1 * s);
}

// ---------------- GEMM: C[M,N] = A[M,K] @ W[N,K]^T (+bias) ----------------
// MODE 0: out fp32 [M][N], no bias
// MODE 1: out bf16 [head][M][128] (head = n>>7, d = n&127), +bias
// MODE 2: out bf16 transposed [n][M], +bias   (for V^T)
static __device__ __forceinline__ void load_tile(const float* a, const float* b, f32x4* av, f32x4* bv) {
#pragma unroll
  for (int i = 0; i < 4; ++i) {
    av[i] = *(const f32x4*)(a + i * 4);
    bv[i] = *(const f32x4*)(b + i * 4);
  }
}
static __device__ __forceinline__ void write_tile(unsigned short* Ar, unsigned short* Br,
                                                  const f32x4* av, const f32x4* bv) {
  u16x8 w0, w1, x0, x1;
#pragma unroll
  for (int j = 0; j < 8; ++j) {
    w0[j] = f2bf(av[(j >> 2)][j & 3]);
    w1[j] = f2bf(av[2 + (j >> 2)][j & 3]);
    x0[j] = f2bf(bv[(j >> 2)][j & 3]);
    x1[j] = f2bf(bv[2 + (j >> 2)][j & 3]);
  }
  *(u16x8*)(Ar) = w0;
  *(u16x8*)(Ar + 8) = w1;
  *(u16x8*)(Br) = x0;
  *(u16x8*)(Br + 8) = x1;
}

template <int MODE>
__global__ __launch_bounds__(256, 2) void gemm_nt(const float* __restrict__ A,
                                                  const float* __restrict__ W,
                                                  const float* __restrict__ bias,
                                                  void* __restrict__ outp,
                                                  int M, int N, int K) {
  __shared__ unsigned short As[2][128][40];   // +8 pad: odd slot stride -> conflict-free b128 reads
  __shared__ unsigned short Bs[2][128][40];
  const int tid = threadIdx.x;
  const int lane = tid & 63;
  const int wv = tid >> 6;
  const int wr = wv >> 1, wc = wv & 1;
  const int lr = lane & 15, lg = lane >> 4;
  const int m0 = blockIdx.x * 128, n0 = blockIdx.y * 128;
  const int sr = tid >> 1;
  const int sk = (tid & 1) * 16;
  const float* Ap = A + (size_t)(m0 + sr) * K + sk;
  const float* Wp = W + (size_t)(n0 + sr) * K + sk;

  f32x4 acc[4][4] = {};
  f32x4 av[4], bv[4];

  const int NK = K >> 5;
  load_tile(Ap, Wp, av, bv);
  write_tile(&As[0][sr][sk], &Bs[0][sr][sk], av, bv);
  __syncthreads();

  int cur = 0;
  for (int kt = 0; kt < NK; ++kt) {
    const bool has_next = (kt + 1 < NK);
    if (has_next) load_tile(Ap + (size_t)(kt + 1) * 32, Wp + (size_t)(kt + 1) * 32, av, bv);

    bf16x8 af[4], bfr[4];
#pragma unroll
    for (int i = 0; i < 4; ++i)
      af[i] = *(const bf16x8*)&As[cur][wr * 64 + i * 16 + lr][lg * 8];
#pragma unroll
    for (int i = 0; i < 4; ++i)
      bfr[i] = *(const bf16x8*)&Bs[cur][wc * 64 + i * 16 + lr][lg * 8];
#pragma unroll
    for (int mi = 0; mi < 4; ++mi)
#pragma unroll
      for (int ni = 0; ni < 4; ++ni)
        acc[mi][ni] = __builtin_amdgcn_mfma_f32_16x16x32_bf16(af[mi], bfr[ni], acc[mi][ni], 0, 0, 0);

    if (has_next) write_tile(&As[cur ^ 1][sr][sk], &Bs[cur ^ 1][sr][sk], av, bv);
    __syncthreads();
    cur ^= 1;
  }

  if (MODE == 0) {
    float* C = (float*)outp;
#pragma unroll
    for (int mi = 0; mi < 4; ++mi) {
      int row = m0 + wr * 64 + mi * 16 + lg * 4;
#pragma unroll
      for (int ni = 0; ni < 4; ++ni) {
        int col = n0 + wc * 64 + ni * 16 + lr;
#pragma unroll
        for (int j = 0; j < 4; ++j)
          C[(size_t)(row + j) * N + col] = acc[mi][ni][j];
      }
    }
  } else if (MODE == 1) {
    unsigned short* O = (unsigned short*)outp;
#pragma unroll
    for (int ni = 0; ni < 4; ++ni) {
      int col = n0 + wc * 64 + ni * 16 + lr;
      float bb = bias[col];
      int head = col >> 7, d = col & 127;
#pragma unroll
      for (int mi = 0; mi < 4; ++mi) {
        int row = m0 + wr * 64 + mi * 16 + lg * 4;
#pragma unroll
        for (int j = 0; j < 4; ++j)
          O[((size_t)head * M + row + j) * HD + d] = f2bf(acc[mi][ni][j] + bb);
      }
    }
  } else {  // MODE 2: transposed out [col][M]
    unsigned short* O = (unsigned short*)outp;
#pragma unroll
    for (int ni = 0; ni < 4; ++ni) {
      int col = n0 + wc * 64 + ni * 16 + lr;
      float bb = bias[col];
#pragma unroll
      for (int mi = 0; mi < 4; ++mi) {
        int row = m0 + wr * 64 + mi * 16 + lg * 4;
        u16x4 pk;
#pragma unroll
        for (int j = 0; j < 4; ++j) pk[j] = f2bf(acc[mi][ni][j] + bb);
        *(u16x4*)&O[(size_t)col * M + row] = pk;
      }
    }
  }
}

// ---------------- Flash attention ----------------
// grid: x = q-tile (S/64), y = head. 4 waves x 16 q-rows. KVBLK = 64.
__global__ __launch_bounds__(256, 2) void attn_fwd(const unsigned short* __restrict__ Qb,
                                                   const unsigned short* __restrict__ Kb,
                                                   const unsigned short* __restrict__ VTb,
                                                   float* __restrict__ Ob) {
  __shared__ unsigned short Kl[64][136];   // [kv][d], +8 pad
  __shared__ unsigned short Vt[128][72];   // [d][kv], +8 pad
  __shared__ unsigned short Pl[4][16][72]; // per-wave P re-layout
  const int tid = threadIdx.x, lane = tid & 63, wv = tid >> 6;
  const int qt = blockIdx.x, h = blockIdx.y;
  const int kh = h >> 2;  // GQA: 4 q-heads per kv-head
  const int q0 = qt * 64;
  const int lr = lane & 15, lg = lane >> 4;

  // Q fragments in registers (16 rows x 128 d per wave)
  bf16x8 qf[4];
  {
    const unsigned short* qp = Qb + ((size_t)h * S_LEN + q0 + wv * 16 + lr) * HD + lg * 8;
#pragma unroll
    for (int s = 0; s < 4; ++s) qf[s] = *(const bf16x8*)(qp + s * 32);
  }

  f32x4 o[8];
#pragma unroll
  for (int i = 0; i < 8; ++i) o[i] = f32x4{0.f, 0.f, 0.f, 0.f};
  float mrow[4] = {-1e30f, -1e30f, -1e30f, -1e30f};
  float lrow[4] = {0.f, 0.f, 0.f, 0.f};
  const float sc = 0.08838834764831845f * 1.44269504088896340f;  // 1/sqrt(128) * log2(e)

  for (int t = 0; t <= qt; ++t) {
    const int c0 = t * 64;
    __syncthreads();
    {
      // stage K tile [64][128]
      int r = tid >> 2, d0 = (tid & 3) * 32;
      const unsigned short* kp = Kb + ((size_t)kh * S_LEN + c0 + r) * HD + d0;
#pragma unroll
      for (int i = 0; i < 4; ++i)
        *(u16x8*)&Kl[r][d0 + i * 8] = *(const u16x8*)(kp + i * 8);
      // stage V^T tile [128][64] (already transposed in global)
      int dd = tid >> 1, koff = (tid & 1) * 32;
      const unsigned short* vp = VTb + ((size_t)(kh * HD + dd)) * S_LEN + c0 + koff;
#pragma unroll
      for (int i = 0; i < 4; ++i)
        *(u16x8*)&Vt[dd][koff + i * 8] = *(const u16x8*)(vp + i * 8);
    }
    __syncthreads();

    // S = Q K^T  (4 col-frags of 16 kv)
    f32x4 sf[4];
#pragma unroll
    for (int c = 0; c < 4; ++c) {
      f32x4 s = {0.f, 0.f, 0.f, 0.f};
#pragma unroll
      for (int ss = 0; ss < 4; ++ss) {
        bf16x8 kf = *(const bf16x8*)&Kl[c * 16 + lr][ss * 32 + lg * 8];
        s = __builtin_amdgcn_mfma_f32_16x16x32_bf16(qf[ss], kf, s, 0, 0, 0);
      }
      sf[c] = s;
    }

    // scale (+ causal mask on diagonal tile), row-max
    float tmax[4] = {-1e30f, -1e30f, -1e30f, -1e30f};
#pragma unroll
    for (int c = 0; c < 4; ++c)
#pragma unroll
      for (int j = 0; j < 4; ++j) {
        float v = sf[c][j] * sc;
        if (t == qt && (c0 + c * 16 + lr) > (q0 + wv * 16 + lg * 4 + j)) v = -1e30f;
        sf[c][j] = v;
        tmax[j] = fmaxf(tmax[j], v);
      }
#pragma unroll
    for (int dlt = 1; dlt < 16; dlt <<= 1)
#pragma unroll
      for (int j = 0; j < 4; ++j)
        tmax[j] = fmaxf(tmax[j], __shfl_xor(tmax[j], dlt, 64));

    float alpha[4];
#pragma unroll
    for (int j = 0; j < 4; ++j) {
      float mn = fmaxf(mrow[j], tmax[j]);
      alpha[j] = exp2f(mrow[j] - mn);
      mrow[j] = mn;
    }
#pragma unroll
    for (int f = 0; f < 8; ++f)
#pragma unroll
      for (int j = 0; j < 4; ++j) o[f][j] *= alpha[j];

    float tsum[4] = {0.f, 0.f, 0.f, 0.f};
#pragma unroll
    for (int c = 0; c < 4; ++c)
#pragma unroll
      for (int j = 0; j < 4; ++j) {
        float p = exp2f(sf[c][j] - mrow[j]);
        tsum[j] += p;
        Pl[wv][lg * 4 + j][c * 16 + lr] = f2bf(p);
      }
#pragma unroll
    for (int dlt = 1; dlt < 16; dlt <<= 1)
#pragma unroll
      for (int j = 0; j < 4; ++j) tsum[j] += __shfl_xor(tsum[j], dlt, 64);
#pragma unroll
    for (int j = 0; j < 4; ++j) lrow[j] = lrow[j] * alpha[j] + tsum[j];

    // PV: o[16 q][128 d] += P[16][64] @ V[64][128]
#pragma unroll
    for (int ks = 0; ks < 2; ++ks) {
      bf16x8 pa = *(const bf16x8*)&Pl[wv][lr][ks * 32 + lg * 8];
#pragma unroll
      for (int df = 0; df < 8; ++df) {
        bf16x8 vb = *(const bf16x8*)&Vt[df * 16 + lr][ks * 32 + lg * 8];
        o[df] = __builtin_amdgcn_mfma_f32_16x16x32_bf16(pa, vb, o[df], 0, 0, 0);
      }
    }
  }

  // normalize + write attn output fp32 [pos][head*128+d]
#pragma unroll
  for (int j = 0; j < 4; ++j) {
    float inv = 1.0f / lrow[j];
    int row = q0 + wv * 16 + lg * 4 + j;
#pragma unroll
    for (int df = 0; df < 8; ++df) {
      int col = h * HD + df * 16 + lr;
      Ob[(size_t)row * (NH * HD) + col] = o[df][j] * inv;
    }
  }
}

// ---------------- launch ----------------
extern "C" void kernel_launch(void* const* d_in, const int* in_sizes, int n_in,
                              void* d_out, int out_size, void* d_ws, size_t ws_size,
                              hipStream_t stream) {
  const float* hidden = (const float*)d_in[0];
  const float* wq = (const float*)d_in[1];
  const float* bq = (const float*)d_in[2];
  const float* wk = (const float*)d_in[3];
  const float* bk = (const float*)d_in[4];
  const float* wv = (const float*)d_in[5];
  const float* bv = (const float*)d_in[6];
  const float* wo = (const float*)d_in[7];
  float* out = (float*)d_out;

  char* p = (char*)d_ws;
  float* cs = (float*)p;                         p += (size_t)S_LEN * 64 * 2 * sizeof(float);   // 1 MB
  unsigned short* Qb = (unsigned short*)p;       p += (size_t)NH * S_LEN * HD * 2;              // 16 MB
  unsigned short* Kbuf = (unsigned short*)p;     p += (size_t)NKV * S_LEN * HD * 2;             // 4 MB
  unsigned short* VTb = (unsigned short*)p;      p += (size_t)NKV * S_LEN * HD * 2;             // 4 MB
  float* attno = (float*)p;                      // 32 MB fp32 [S][NH*HD]

  hipLaunchKernelGGL(rope_table, dim3((S_LEN * 64 + 255) / 256), dim3(256), 0, stream, cs);
  hipLaunchKernelGGL((gemm_nt<1>), dim3(16, 32), dim3(256), 0, stream, hidden, wq, bq, (void*)Qb, 2048, 4096, 4096);
  hipLaunchKernelGGL((gemm_nt<1>), dim3(16, 8), dim3(256), 0, stream, hidden, wk, bk, (void*)Kbuf, 2048, 1024, 4096);
  hipLaunchKernelGGL((gemm_nt<2>), dim3(16, 8), dim3(256), 0, stream, hidden, wv, bv, (void*)VTb, 2048, 1024, 4096);
  hipLaunchKernelGGL(rope_apply, dim3(NH * S_LEN * 64 / 256), dim3(256), 0, stream, Qb, cs, NH * S_LEN * 64);
  hipLaunchKernelGGL(rope_apply, dim3(NKV * S_LEN * 64 / 256), dim3(256), 0, stream, Kbuf, cs, NKV * S_LEN * 64);
  hipLaunchKernelGGL(attn_fwd, dim3(32, 32), dim3(256), 0, stream, Qb, Kbuf, VTb, attno);
  hipLaunchKernelGGL((gemm_nt<0>), dim3(16, 32), dim3(256), 0, stream, attno, wo, (const float*)nullptr, (void*)out, 2048, 4096, 4096);
}

// Round 2
// 384.708 us; speedup vs baseline: 1.9614x; 1.9614x over previous
//
#include <hip/hip_runtime.h>
#include <hip/hip_bf16.h>

#define S_LEN 2048
#define HID 4096
#define NH 32
#define NKV 8
#define HD 128

typedef __attribute__((ext_vector_type(4))) float f32x4;
typedef __attribute__((ext_vector_type(8))) __bf16 bf16x8;
typedef __attribute__((ext_vector_type(8))) unsigned short u16x8;
typedef __attribute__((ext_vector_type(4))) unsigned short u16x4;

static __device__ __forceinline__ unsigned short f2bf(float x) {
  return __builtin_bit_cast(unsigned short, __float2bfloat16(x));
}
static __device__ __forceinline__ float bf2f(unsigned short u) {
  return __builtin_bit_cast(float, (unsigned int)u << 16);
}
// async global->LDS, 16B per lane; LDS dest must be wave-uniform base (linear fill)
static __device__ __forceinline__ void gld16(const unsigned short* g, unsigned short* l) {
  __builtin_amdgcn_global_load_lds(
      (const __attribute__((address_space(1))) unsigned int*)g,
      (__attribute__((address_space(3))) unsigned int*)l, 16, 0, 0);
}

// ---------------- fp32 -> bf16 bulk convert ----------------
__global__ void f2bf_kernel(const float* __restrict__ in, unsigned short* __restrict__ out, int n8) {
  int i = blockIdx.x * 256 + threadIdx.x;
  if (i >= n8) return;
  f32x4 a = ((const f32x4*)in)[(size_t)i * 2];
  f32x4 b = ((const f32x4*)in)[(size_t)i * 2 + 1];
  u16x8 w;
#pragma unroll
  for (int j = 0; j < 4; ++j) {
    w[j] = f2bf(a[j]);
    w[4 + j] = f2bf(b[j]);
  }
  ((u16x8*)out)[(size_t)i] = w;
}

// ---------------- RoPE table ----------------
__global__ void rope_table(float* cs) {
  int idx = blockIdx.x * blockDim.x + threadIdx.x;
  if (idx >= S_LEN * 64) return;
  int d = idx & 63;
  int p = idx >> 6;
  float invf = exp2f(-(float)d * (19.9315685693241741f / 64.0f));  // theta^-d/64, log2(1e6)
  float ang = (float)p * invf;
  cs[idx] = cosf(ang);
  cs[S_LEN * 64 + idx] = sinf(ang);
}

// ---------------- RoPE apply (in-place, bf16 [head][S][128]) ----------------
__global__ void rope_apply(unsigned short* __restrict__ buf, const float* __restrict__ cs, int total) {
  int idx = blockIdx.x * blockDim.x + threadIdx.x;
  if (idx >= total) return;  // total = nheads * S * 64
  int d = idx & 63;
  int hp = idx >> 6;
  int pos = hp & (S_LEN - 1);
  size_t base = (size_t)hp * HD;
  float c = cs[pos * 64 + d];
  float s = cs[S_LEN * 64 + pos * 64 + d];
  float x1 = bf2f(buf[base + d]);
  float x2 = bf2f(buf[base + 64 + d]);
  buf[base + d] = f2bf(x1 * c - x2 * s);
  buf[base + 64 + d] = f2bf(x2 * c + x1 * s);
}

// ---------------- GEMM: C[2048,N] = A[2048,4096] @ W[N,4096]^T ----------------
// m97 structure: 128x128 tile, BK=32, global_load_lds(16B), 2 barriers/K-step.
// MODE 0: Cout fp32, no bias (out-projection)
// MODE 1: fused QKV epilogue -> Qb/Kb (bf16 [head][S][128], +bias), VTb (bf16 [n][S], +bias)
template <int MODE>
__global__ __launch_bounds__(256) void gemm_nt(
    const unsigned short* __restrict__ A, const unsigned short* __restrict__ W,
    const float* __restrict__ bq, const float* __restrict__ bk, const float* __restrict__ bv,
    unsigned short* __restrict__ Qb, unsigned short* __restrict__ Kb,
    unsigned short* __restrict__ VTb, float* __restrict__ Cout) {
  __shared__ unsigned short As[4096];  // [128][32] linear (global_load_lds needs linear fill)
  __shared__ unsigned short Bs[4096];
  // XCD-chunked swizzle (grid product is a multiple of 8)
  int lin = blockIdx.x + 16 * blockIdx.y;
  int cpx = (16 * gridDim.y) >> 3;
  int swz = (lin & 7) * cpx + (lin >> 3);
  const int m0 = (swz & 15) * 128;
  const int n0 = (swz >> 4) * 128;
  const int tid = threadIdx.x, lane = tid & 63, wv = tid >> 6;
  const int wr = wv >> 1, wc = wv & 1;
  const int lr = lane & 15, lg = lane >> 4;
  const int srow = lane >> 2, skk = (lane & 3) * 8;

  const unsigned short* Ag0 = A + (size_t)(m0 + wv * 32 + srow) * HID + skk;
  const unsigned short* Ag1 = Ag0 + (size_t)16 * HID;
  const unsigned short* Wg0 = W + (size_t)(n0 + wv * 32 + srow) * HID + skk;
  const unsigned short* Wg1 = Wg0 + (size_t)16 * HID;
  unsigned short* Al0 = As + wv * 1024;  // wave-uniform LDS slice bases
  unsigned short* Al1 = As + wv * 1024 + 512;
  unsigned short* Bl0 = Bs + wv * 1024;
  unsigned short* Bl1 = Bs + wv * 1024 + 512;

  f32x4 acc[4][4] = {};

  for (int kt = 0; kt < HID / 32; ++kt) {
    const int ko = kt * 32;
    gld16(Ag0 + ko, Al0);
    gld16(Ag1 + ko, Al1);
    gld16(Wg0 + ko, Bl0);
    gld16(Wg1 + ko, Bl1);
    __syncthreads();  // drains vmcnt -> tile visible
    bf16x8 af[4], bfr[4];
#pragma unroll
    for (int i = 0; i < 4; ++i)
      af[i] = *(const bf16x8*)&As[(wr * 64 + i * 16 + lr) * 32 + lg * 8];
#pragma unroll
    for (int i = 0; i < 4; ++i)
      bfr[i] = *(const bf16x8*)&Bs[(wc * 64 + i * 16 + lr) * 32 + lg * 8];
#pragma unroll
    for (int mi = 0; mi < 4; ++mi)
#pragma unroll
      for (int ni = 0; ni < 4; ++ni)
        acc[mi][ni] = __builtin_amdgcn_mfma_f32_16x16x32_bf16(af[mi], bfr[ni], acc[mi][ni], 0, 0, 0);
    __syncthreads();  // reads done -> next stage may overwrite
  }

  if (MODE == 0) {
#pragma unroll
    for (int mi = 0; mi < 4; ++mi) {
      int row = m0 + wr * 64 + mi * 16 + lg * 4;
#pragma unroll
      for (int ni = 0; ni < 4; ++ni) {
        int col = n0 + wc * 64 + ni * 16 + lr;
#pragma unroll
        for (int j = 0; j < 4; ++j)
          Cout[(size_t)(row + j) * HID + col] = acc[mi][ni][j];
      }
    }
  } else {
    unsigned short* obuf;
    const float* bptr;
    int cbase;
    bool transp = false;
    if (n0 < 4096) { obuf = Qb; bptr = bq; cbase = n0; }
    else if (n0 < 5120) { obuf = Kb; bptr = bk; cbase = n0 - 4096; }
    else { obuf = VTb; bptr = bv; cbase = n0 - 5120; transp = true; }
#pragma unroll
    for (int ni = 0; ni < 4; ++ni) {
      int c = cbase + wc * 64 + ni * 16 + lr;
      float bb = bptr[c];
      if (!transp) {
        int head = c >> 7, d = c & 127;
#pragma unroll
        for (int mi = 0; mi < 4; ++mi) {
          int row = m0 + wr * 64 + mi * 16 + lg * 4;
#pragma unroll
          for (int j = 0; j < 4; ++j)
            obuf[((size_t)head * S_LEN + row + j) * HD + d] = f2bf(acc[mi][ni][j] + bb);
        }
      } else {
#pragma unroll
        for (int mi = 0; mi < 4; ++mi) {
          int row = m0 + wr * 64 + mi * 16 + lg * 4;
          u16x4 pk;
#pragma unroll
          for (int j = 0; j < 4; ++j) pk[j] = f2bf(acc[mi][ni][j] + bb);
          *(u16x4*)&obuf[(size_t)c * S_LEN + row] = pk;
        }
      }
    }
  }
}

// ---------------- Flash attention ----------------
// grid (16, 32): x = balanced pair (handles q-tiles p and 31-p, always 33 KV tiles),
// y = head. 4 waves x 16 q-rows, KVBLK=64, T14 register prefetch of next K/V tile.
__global__ __launch_bounds__(256) void attn_fwd(const unsigned short* __restrict__ Qb,
                                                const unsigned short* __restrict__ Kb,
                                                const unsigned short* __restrict__ VTb,
                                                unsigned short* __restrict__ Ob) {
  __shared__ unsigned short Kl[64][136];
  __shared__ unsigned short Vt[128][72];
  __shared__ unsigned short Pl[4][16][72];
  int lin = blockIdx.x + 16 * blockIdx.y;
  int swz = (lin & 7) * 64 + (lin >> 3);  // XCD-chunked: each XCD owns 4 heads = 1 kv-head
  const int pair = swz & 15;
  const int h = swz >> 4;
  const int kh = h >> 2;
  const int tid = threadIdx.x, lane = tid & 63, wv = tid >> 6;
  const int lr = lane & 15, lg = lane >> 4;
  const int kr_row = tid >> 2, kr_d = (tid & 3) * 32;
  const int vr_d = tid >> 1, vr_k = (tid & 1) * 32;
  const unsigned short* Kbase = Kb + (size_t)kh * S_LEN * HD;
  const unsigned short* Vbase = VTb + (size_t)kh * HD * S_LEN;
  const float sc = 0.08838834764831845f * 1.44269504088896340f;  // 1/sqrt(128)*log2e

  for (int half = 0; half < 2; ++half) {
    const int qt = half ? 31 - pair : pair;
    const int q0 = qt * 64;
    bf16x8 qf[4];
    {
      const unsigned short* qp = Qb + ((size_t)h * S_LEN + q0 + wv * 16 + lr) * HD + lg * 8;
#pragma unroll
      for (int s = 0; s < 4; ++s) qf[s] = *(const bf16x8*)(qp + s * 32);
    }
    f32x4 o[8];
#pragma unroll
    for (int i = 0; i < 8; ++i) o[i] = f32x4{0.f, 0.f, 0.f, 0.f};
    float mrow[4] = {-1e30f, -1e30f, -1e30f, -1e30f};
    float lrow[4] = {0.f, 0.f, 0.f, 0.f};

    // prefetch tile 0 into regs
    u16x8 kreg[4], vreg[4];
    {
      const unsigned short* kp = Kbase + (size_t)kr_row * HD + kr_d;
      const unsigned short* vp = Vbase + (size_t)vr_d * S_LEN + vr_k;
#pragma unroll
      for (int i = 0; i < 4; ++i) kreg[i] = *(const u16x8*)(kp + i * 8);
#pragma unroll
      for (int i = 0; i < 4; ++i) vreg[i] = *(const u16x8*)(vp + i * 8);
    }
    __syncthreads();  // prior half's LDS reads complete
#pragma unroll
    for (int i = 0; i < 4; ++i) *(u16x8*)&Kl[kr_row][kr_d + i * 8] = kreg[i];
#pragma unroll
    for (int i = 0; i < 4; ++i) *(u16x8*)&Vt[vr_d][vr_k + i * 8] = vreg[i];
    __syncthreads();

    for (int t = 0; t <= qt; ++t) {
      // T14: issue next tile's global loads now; latency hides under compute
      if (t < qt) {
        const unsigned short* kp = Kbase + ((size_t)(t + 1) * 64 + kr_row) * HD + kr_d;
        const unsigned short* vp = Vbase + (size_t)vr_d * S_LEN + (t + 1) * 64 + vr_k;
#pragma unroll
        for (int i = 0; i < 4; ++i) kreg[i] = *(const u16x8*)(kp + i * 8);
#pragma unroll
        for (int i = 0; i < 4; ++i) vreg[i] = *(const u16x8*)(vp + i * 8);
      }
      const int c0 = t * 64;
      // S = Q K^T
      f32x4 sf[4];
      __builtin_amdgcn_s_setprio(1);
#pragma unroll
      for (int c = 0; c < 4; ++c) {
        f32x4 s = {0.f, 0.f, 0.f, 0.f};
#pragma unroll
        for (int ss = 0; ss < 4; ++ss) {
          bf16x8 kf = *(const bf16x8*)&Kl[c * 16 + lr][ss * 32 + lg * 8];
          s = __builtin_amdgcn_mfma_f32_16x16x32_bf16(qf[ss], kf, s, 0, 0, 0);
        }
        sf[c] = s;
      }
      __builtin_amdgcn_s_setprio(0);

      // scale + causal mask + online softmax
      float tmax[4] = {-1e30f, -1e30f, -1e30f, -1e30f};
#pragma unroll
      for (int c = 0; c < 4; ++c)
#pragma unroll
        for (int j = 0; j < 4; ++j) {
          float v = sf[c][j] * sc;
          if (t == qt && (c0 + c * 16 + lr) > (q0 + wv * 16 + lg * 4 + j)) v = -1e30f;
          sf[c][j] = v;
          tmax[j] = fmaxf(tmax[j], v);
        }
#pragma unroll
      for (int dlt = 1; dlt < 16; dlt <<= 1)
#pragma unroll
        for (int j = 0; j < 4; ++j)
          tmax[j] = fmaxf(tmax[j], __shfl_xor(tmax[j], dlt, 64));
      float alpha[4];
#pragma unroll
      for (int j = 0; j < 4; ++j) {
        float mn = fmaxf(mrow[j], tmax[j]);
        alpha[j] = exp2f(mrow[j] - mn);
        mrow[j] = mn;
      }
#pragma unroll
      for (int f = 0; f < 8; ++f)
#pragma unroll
        for (int j = 0; j < 4; ++j) o[f][j] *= alpha[j];
      float tsum[4] = {0.f, 0.f, 0.f, 0.f};
#pragma unroll
      for (int c = 0; c < 4; ++c)
#pragma unroll
        for (int j = 0; j < 4; ++j) {
          float p = exp2f(sf[c][j] - mrow[j]);
          tsum[j] += p;
          Pl[wv][lg * 4 + j][c * 16 + lr] = f2bf(p);
        }
#pragma unroll
      for (int dlt = 1; dlt < 16; dlt <<= 1)
#pragma unroll
        for (int j = 0; j < 4; ++j) tsum[j] += __shfl_xor(tsum[j], dlt, 64);
#pragma unroll
      for (int j = 0; j < 4; ++j) lrow[j] = lrow[j] * alpha[j] + tsum[j];

      // PV
      __builtin_amdgcn_s_setprio(1);
#pragma unroll
      for (int ks = 0; ks < 2; ++ks) {
        bf16x8 pa = *(const bf16x8*)&Pl[wv][lr][ks * 32 + lg * 8];
#pragma unroll
        for (int df = 0; df < 8; ++df) {
          bf16x8 vb = *(const bf16x8*)&Vt[df * 16 + lr][ks * 32 + lg * 8];
          o[df] = __builtin_amdgcn_mfma_f32_16x16x32_bf16(pa, vb, o[df], 0, 0, 0);
        }
      }
      __builtin_amdgcn_s_setprio(0);

      if (t < qt) {
        __syncthreads();  // all waves done reading current tile
#pragma unroll
        for (int i = 0; i < 4; ++i) *(u16x8*)&Kl[kr_row][kr_d + i * 8] = kreg[i];
#pragma unroll
        for (int i = 0; i < 4; ++i) *(u16x8*)&Vt[vr_d][vr_k + i * 8] = vreg[i];
        __syncthreads();
      }
    }

    // normalize + write bf16 attn output [pos][head*128+d]
#pragma unroll
    for (int j = 0; j < 4; ++j) {
      float inv = 1.0f / lrow[j];
      int row = q0 + wv * 16 + lg * 4 + j;
#pragma unroll
      for (int df = 0; df < 8; ++df)
        Ob[(size_t)row * (NH * HD) + h * HD + df * 16 + lr] = f2bf(o[df][j] * inv);
    }
  }
}

// ---------------- launch ----------------
extern "C" void kernel_launch(void* const* d_in, const int* in_sizes, int n_in,
                              void* d_out, int out_size, void* d_ws, size_t ws_size,
                              hipStream_t stream) {
  const float* hidden = (const float*)d_in[0];
  const float* wq = (const float*)d_in[1];
  const float* bq = (const float*)d_in[2];
  const float* wk = (const float*)d_in[3];
  const float* bk = (const float*)d_in[4];
  const float* wv = (const float*)d_in[5];
  const float* bv = (const float*)d_in[6];
  const float* wo = (const float*)d_in[7];
  float* out = (float*)d_out;

  char* p = (char*)d_ws;
  float* cs = (float*)p;                    p += (size_t)1 << 20;         // 1 MB rope table
  unsigned short* hb = (unsigned short*)p;  p += (size_t)16 << 20;        // hidden bf16
  unsigned short* Qb = (unsigned short*)p;  p += (size_t)16 << 20;        // Q [32][2048][128]
  unsigned short* Kbuf = (unsigned short*)p; p += (size_t)4 << 20;        // K [8][2048][128]
  unsigned short* VTb = (unsigned short*)p; p += (size_t)4 << 20;         // V^T [1024][2048]
  unsigned short* attno = (unsigned short*)p; p += (size_t)16 << 20;      // attn out bf16
  unsigned short* wbuf = (unsigned short*)p;                              // 48 MB, reused (qkv then wo)

  hipLaunchKernelGGL(rope_table, dim3(512), dim3(256), 0, stream, cs);
  hipLaunchKernelGGL(f2bf_kernel, dim3(4096), dim3(256), 0, stream, hidden, hb, S_LEN * HID / 8);
  hipLaunchKernelGGL(f2bf_kernel, dim3(8192), dim3(256), 0, stream, wq, wbuf, 4096 * HID / 8);
  hipLaunchKernelGGL(f2bf_kernel, dim3(2048), dim3(256), 0, stream, wk, wbuf + (size_t)4096 * HID, 1024 * HID / 8);
  hipLaunchKernelGGL(f2bf_kernel, dim3(2048), dim3(256), 0, stream, wv, wbuf + (size_t)5120 * HID, 1024 * HID / 8);
  hipLaunchKernelGGL((gemm_nt<1>), dim3(16, 48), dim3(256), 0, stream,
                     hb, wbuf, bq, bk, bv, Qb, Kbuf, VTb, (float*)nullptr);
  hipLaunchKernelGGL(rope_apply, dim3(16384), dim3(256), 0, stream, Qb, cs, NH * S_LEN * 64);
  hipLaunchKernelGGL(rope_apply, dim3(4096), dim3(256), 0, stream, Kbuf, cs, NKV * S_LEN * 64);
  hipLaunchKernelGGL(attn_fwd, dim3(16, 32), dim3(256), 0, stream, Qb, Kbuf, VTb, attno);
  hipLaunchKernelGGL(f2bf_kernel, dim3(8192), dim3(256), 0, stream, wo, wbuf, 4096 * HID / 8);
  hipLaunchKernelGGL((gemm_nt<0>), dim3(16, 32), dim3(256), 0, stream,
                     attno, wbuf, (const float*)nullptr, (const float*)nullptr, (const float*)nullptr,
                     (unsigned short*)nullptr, (unsigned short*)nullptr, (unsigned short*)nullptr, out);
}